// Round 3
// baseline (15531.256 us; speedup 1.0000x reference)
//
#include <hip/hip_runtime.h>

// Problem constants
#define B_   32
#define T_   256
#define N_   128
#define DIN_ 16
#define U_   64

// LDS layout (ushort elements)
#define PD 392   // node-major diffusion buffer pitch (>=384, +8 stagger)
#define PT 136   // ch-major (transposed) buffer pitch (>=128, +8 stagger)
#define LDS_US  (N_*PD + N_*PT)
#define LDS_BYTES (LDS_US*2)     // 135168 B

// Workspace (ushort elems): WT[co][k], k-order: [dm0 c | (dm1,dm2) interleaved]
#define WT0G_OFF 0
#define WT0C_OFF (128*256)
#define WT1G_OFF (WT0C_OFF + 64*256)
#define WT1C_OFF (WT1G_OFF + 128*384)
#define WT_TOTAL (WT1C_OFF + 64*384)   // 122880 ushorts
#define S2_OFF   WT_TOTAL              // bf16 S2[128][128]

typedef __attribute__((ext_vector_type(8))) short bfrag;          // 8 bf16 (4 VGPR)
typedef __attribute__((ext_vector_type(4))) float ffrag;          // MFMA C/D
typedef __attribute__((ext_vector_type(4))) unsigned short us4;
typedef __attribute__((ext_vector_type(2))) unsigned short us2;

__device__ __forceinline__ unsigned short f2b(float x) {          // fp32 -> bf16 RNE
  union { float f; unsigned u; } v; v.f = x;
  return (unsigned short)((v.u + 0x7fffu + ((v.u >> 16) & 1u)) >> 16);
}
__device__ __forceinline__ float sigm(float x) {
  float e = __expf(-x);
  return __builtin_amdgcn_rcpf(1.f + e);
}
__device__ __forceinline__ float tanh_(float x) {
  float e = __expf(2.f * x);   // tanh = 1 - 2/(1+e^{2x}); saturates cleanly
  return 1.f - 2.f * __builtin_amdgcn_rcpf(1.f + e);
}

// k-order: k<cin -> dm0 (W0 - W2 fold); else j=k-cin: c=j>>1, j&1==0 -> W1, else 2*W2
// (x2 = 2*S2@xc - xc with S2 precomputed; -xc and 2* absorbed into weights)
__device__ __forceinline__ float wval(const float* w, int ncol, int cin,
                                      int co, int k) {
  if (k >= 3*cin) return 0.f;             // zero K-pad (L0: 240 -> 256)
  if (k < cin) return w[(k*3 + 0)*ncol + co] - w[(k*3 + 2)*ncol + co];
  int j = k - cin, c = j >> 1;
  if ((j & 1) == 0) return w[(c*3 + 1)*ncol + co];
  return 2.f * w[(c*3 + 2)*ncol + co];
}

__global__ void setup_wt(const float* __restrict__ w0g, const float* __restrict__ w0c,
                         const float* __restrict__ w1g, const float* __restrict__ w1c,
                         unsigned short* __restrict__ wt) {
  int i = blockIdx.x * blockDim.x + threadIdx.x;
  if (i >= WT_TOTAL) return;
  float v;
  if (i < WT0C_OFF) {
    int co = i >> 8, k = i & 255;
    v = wval(w0g, 128, 80, co, k);
  } else if (i < WT1G_OFF) {
    int j = i - WT0C_OFF; int co = j >> 8, k = j & 255;
    v = wval(w0c, 64, 80, co, k);
  } else if (i < WT1C_OFF) {
    int j = i - WT1G_OFF; int co = j / 384, k = j - co*384;
    v = wval(w1g, 128, 128, co, k);
  } else {
    int j = i - WT1C_OFF; int co = j / 384, k = j - co*384;
    v = wval(w1c, 64, 128, co, k);
  }
  wt[i] = f2b(v);
}

__global__ void setup_s2(const float* __restrict__ sup, unsigned short* __restrict__ s2) {
  int idx = blockIdx.x * blockDim.x + threadIdx.x;   // 16384
  int i = idx >> 7, j = idx & 127;
  float acc = 0.f;
#pragma unroll 4
  for (int k = 0; k < 128; ++k) acc += sup[i*128 + k] * sup[k*128 + j];
  s2[idx] = f2b(acc);
}

// Weight GEMM: wave owns a 16-node m-tile (arow) and NT co-tiles (compile-time list).
// B streamed from global WT (L2-resident).
template<int KT, int NT>
__device__ __forceinline__ void wgemm(ffrag (&acc)[NT], const int (&tiles)[NT],
    const unsigned short* __restrict__ arow,
    const unsigned short* __restrict__ wtp, const int Kpad,
    const int ln, const int lq) {
  const ffrag fz = {0.f, 0.f, 0.f, 0.f};
#pragma unroll
  for (int n = 0; n < NT; ++n) acc[n] = fz;
#pragma unroll 2
  for (int ks = 0; ks < KT; ++ks) {
    bfrag a = *(const bfrag*)&arow[32*ks + 8*lq];
#pragma unroll
    for (int n = 0; n < NT; ++n) {
      bfrag bw = *(const bfrag*)&wtp[(16*tiles[n] + ln)*Kpad + 32*ks + 8*lq];
      acc[n] = __builtin_amdgcn_mfma_f32_16x16x32_bf16(a, bw, acc[n], 0,0,0);
    }
  }
}

__global__ __launch_bounds__(1024, 4) void dcgru(
    const float* __restrict__ xseq, const int* __restrict__ slen,
    const float* __restrict__ sup,
    const float* __restrict__ b0g, const float* __restrict__ b0c,
    const float* __restrict__ b1g, const float* __restrict__ b1c,
    const float* __restrict__ wfc, const float* __restrict__ bfc,
    const unsigned short* __restrict__ wt, float* __restrict__ out) {
  extern __shared__ unsigned short lds[];
  unsigned short* diffb = lds;             // [128][PD] node-major A-operand buffer
  unsigned short* difT  = lds + N_*PD;     // [128][PT] ch-major (diffuse B operand)
  const int b   = blockIdx.x;
  const int tid = threadIdx.x;
  const int w   = tid >> 6;                // wave 0..15
  const int s   = w >> 1;                  // node strip: nodes [16s, 16s+16)
  const int e   = w & 1;                   // channel half
  const int ln  = tid & 15;
  const int lq  = (tid >> 4) & 3;
  const int L   = slen[b];
  const unsigned short* __restrict__ arow = diffb + (16*s + ln)*PD;

  // ---- S and S2 A-frags for this wave's 16-row strip (8 bfrags = 32 VGPR) ----
  bfrag Sf[4], S2f[4];
#pragma unroll
  for (int ks = 0; ks < 4; ++ks) {
    const float* p = sup + (16*s + ln)*N_ + 32*ks + 8*lq;
    union { bfrag v; unsigned short u[8]; } tmp;
#pragma unroll
    for (int j = 0; j < 8; ++j) tmp.u[j] = f2b(p[j]);
    Sf[ks] = tmp.v;
    S2f[ks] = *(const bfrag*)&wt[S2_OFF + (16*s + ln)*N_ + 32*ks + 8*lq];
  }

  // fp32 master hidden (this wave's node strip x channel half 32e..32e+31):
  // value[node = 16s + 4*lq + r][ch = 16*(2e+i) + ln]
  ffrag h0m[2], h1m[2];
  const ffrag fz = {0.f, 0.f, 0.f, 0.f};
#pragma unroll
  for (int i = 0; i < 2; ++i) { h0m[i] = fz; h1m[i] = fz; }

  // zero L0 K-pad cols [240,256) once
  for (int i = tid; i < N_*16; i += 1024)
    diffb[(i >> 4)*PD + 240 + (i & 15)] = 0;

  // Diffusion for ch tile nt: dm1 = S@xc, dm2 = S2@xc -> interleaved cols
  // dbase + 2*ch + {0,1}. One difT B-frag feeds both MFMA chains.
  auto diffuse = [&](int nt, int dbase) {
    ffrag a1 = fz, a2 = fz;
#pragma unroll
    for (int ks = 0; ks < 4; ++ks) {
      bfrag bf = *(const bfrag*)&difT[(16*nt + ln)*PT + 32*ks + 8*lq];
      a1 = __builtin_amdgcn_mfma_f32_16x16x32_bf16(Sf[ks],  bf, a1, 0,0,0);
      a2 = __builtin_amdgcn_mfma_f32_16x16x32_bf16(S2f[ks], bf, a2, 0,0,0);
    }
    const int node0 = 16*s + 4*lq;
    const int col = dbase + 2*(16*nt + ln);
#pragma unroll
    for (int r = 0; r < 4; ++r) {
      us2 p = {f2b(a1[r]), f2b(a2[r])};
      *(us2*)&diffb[(node0 + r)*PD + col] = p;    // aligned b32 write
    }
  };

  // Dump this wave's half-tile (2 ffrags) into both LDS layouts at ch base cb.
  auto dumpH = [&](ffrag (&v)[2], int cb) {
    const int node0 = 16*s + 4*lq;
#pragma unroll
    for (int i = 0; i < 2; ++i) {
      const int ch = cb + 16*(2*e + i) + ln;
      unsigned short sv[4];
#pragma unroll
      for (int r = 0; r < 4; ++r) sv[r] = f2b(v[i][r]);
#pragma unroll
      for (int r = 0; r < 4; ++r) diffb[(node0 + r)*PD + ch] = sv[r];
      us4 p4 = {sv[0], sv[1], sv[2], sv[3]};
      *(us4*)&difT[ch*PT + node0] = p4;
    }
  };

  // x prefetch: 2 floats/thread
  float2 xv = *(const float2*)&xseq[(size_t)(b*T_)*N_*DIN_ + 2*tid];

#pragma clang loop unroll(disable)
  for (int t = 0; t < L; ++t) {
    ffrag u0s[2], u1s[2];
    // ---------------- Layer 0 (cols: x 0..15 | h 16..79 | dm12 80..239) -------
    {  // stage x_t from prefetched regs
      const int f = 2*tid;
      const int node = f >> 4, c = f & 15;
      unsigned short s0 = f2b(xv.x), s1 = f2b(xv.y);
      us2 q = {s0, s1};
      *(us2*)&diffb[node*PD + c] = q;
      difT[c*PT + node] = s0; difT[(c+1)*PT + node] = s1;
    }
    dumpH(h0m, DIN_);
    {  // prefetch x_{t+1} (clamped; deterministic work every call)
      int tn = t + 1 < L ? t + 1 : L - 1;
      xv = *(const float2*)&xseq[(size_t)(b*T_ + tn)*N_*DIN_ + 2*tid];
    }
    __syncthreads();                                   // B1
    if (e == 0) { diffuse(0, 80); diffuse(1, 80); diffuse(2, 80); }
    else        { diffuse(3, 80); diffuse(4, 80); }
    __syncthreads();                                   // B2
    {
      const int gt[4] = {2*e, 2*e + 1, 2*e + 4, 2*e + 5};
      float bg[4];
#pragma unroll
      for (int n = 0; n < 4; ++n) bg[n] = b0g[16*gt[n] + ln];
      ffrag ga[4];
      wgemm<8, 4>(ga, gt, arow, wt + WT0G_OFF, 256, ln, lq);
      ffrag rh[2];
#pragma unroll
      for (int i = 0; i < 2; ++i)
#pragma unroll
        for (int r = 0; r < 4; ++r) {
          float rr = sigm(ga[i][r] + bg[i]);
          rh[i][r] = rr * h0m[i][r];
          u0s[i][r] = sigm(ga[2+i][r] + bg[2+i]);
        }
      __syncthreads();                                 // B2.5 (rh write vs h read)
      dumpH(rh, DIN_);
    }
    __syncthreads();                                   // B3
    if (e == 0) { diffuse(1, 80); diffuse(2, 80); }
    else        { diffuse(3, 80); diffuse(4, 80); }
    __syncthreads();                                   // B4
    {
      const int ct[2] = {2*e, 2*e + 1};
      float bc[2];
#pragma unroll
      for (int n = 0; n < 2; ++n) bc[n] = b0c[16*ct[n] + ln];
      ffrag ca[2];
      wgemm<8, 2>(ca, ct, arow, wt + WT0C_OFF, 256, ln, lq);
#pragma unroll
      for (int i = 0; i < 2; ++i)
#pragma unroll
        for (int r = 0; r < 4; ++r) {
          float cc = tanh_(ca[i][r] + bc[i]);
          float uu = u0s[i][r];
          h0m[i][r] = uu*h0m[i][r] + (1.f - uu)*cc;
        }
    }
    __syncthreads();                                   // B4.5 (stage vs cand read)
    // ---------------- Layer 1 (cols: h0' 0..63 | h1 64..127 | dm12 128..383) --
    dumpH(h0m, 0);
    dumpH(h1m, 64);
    __syncthreads();                                   // B5
    {
      const int n0 = 4*e;
      diffuse(n0, 128); diffuse(n0+1, 128); diffuse(n0+2, 128); diffuse(n0+3, 128);
    }
    __syncthreads();                                   // B6
    {
      const int gt[4] = {2*e, 2*e + 1, 2*e + 4, 2*e + 5};
      float bg[4];
#pragma unroll
      for (int n = 0; n < 4; ++n) bg[n] = b1g[16*gt[n] + ln];
      ffrag ga[4];
      wgemm<12, 4>(ga, gt, arow, wt + WT1G_OFF, 384, ln, lq);
      ffrag rh[2];
#pragma unroll
      for (int i = 0; i < 2; ++i)
#pragma unroll
        for (int r = 0; r < 4; ++r) {
          float rr = sigm(ga[i][r] + bg[i]);
          rh[i][r] = rr * h1m[i][r];
          u1s[i][r] = sigm(ga[2+i][r] + bg[2+i]);
        }
      __syncthreads();                                 // B6.5
      dumpH(rh, 64);
    }
    __syncthreads();                                   // B7
    { const int n0 = 4 + 2*e; diffuse(n0, 128); diffuse(n0+1, 128); }
    __syncthreads();                                   // B8
    {
      const int ct[2] = {2*e, 2*e + 1};
      float bc[2];
#pragma unroll
      for (int n = 0; n < 2; ++n) bc[n] = b1c[16*ct[n] + ln];
      ffrag ca[2];
      wgemm<12, 2>(ca, ct, arow, wt + WT1C_OFF, 384, ln, lq);
#pragma unroll
      for (int i = 0; i < 2; ++i)
#pragma unroll
        for (int r = 0; r < 4; ++r) {
          float cc = tanh_(ca[i][r] + bc[i]);
          float uu = u1s[i][r];
          h1m[i][r] = uu*h1m[i][r] + (1.f - uu)*cc;
        }
    }
    __syncthreads();                                   // B8.5 (next stage vs reads)
  }

  // ---------------- Head: relu(h1) @ W_fc + b_fc, max over nodes --------------
  {
    float* hb = (float*)lds;                 // [128][64] relu'd last hidden
    const int node0 = 16*s + 4*lq;
#pragma unroll
    for (int i = 0; i < 2; ++i)
#pragma unroll
      for (int r = 0; r < 4; ++r) {
        float v = h1m[i][r];
        hb[(node0 + r)*U_ + 16*(2*e + i) + ln] = v > 0.f ? v : 0.f;
      }
  }
  __syncthreads();
  float* hb = (float*)lds;
  float* lb = hb + N_*U_;                    // [128][4] logits
  if (tid < N_) {
    float lg[4];
#pragma unroll
    for (int j = 0; j < 4; ++j) lg[j] = bfc[j];
    for (int ch = 0; ch < U_; ++ch) {
      float v = hb[tid*U_ + ch];
#pragma unroll
      for (int j = 0; j < 4; ++j) lg[j] += v * wfc[ch*4 + j];
    }
#pragma unroll
    for (int j = 0; j < 4; ++j) lb[tid*4 + j] = lg[j];
  }
  __syncthreads();
  if (tid < 4) {
    float m = lb[tid];
    for (int n = 1; n < N_; ++n) m = fmaxf(m, lb[n*4 + tid]);
    out[b*4 + tid] = m;
  }
}

extern "C" void kernel_launch(void* const* d_in, const int* in_sizes, int n_in,
                              void* d_out, int out_size, void* d_ws, size_t ws_size,
                              hipStream_t stream) {
  const float* xseq = (const float*)d_in[0];
  const int*   slen = (const int*)  d_in[1];
  const float* sup  = (const float*)d_in[2];
  const float* w0g  = (const float*)d_in[3];
  const float* b0g  = (const float*)d_in[4];
  const float* w0c  = (const float*)d_in[5];
  const float* b0c  = (const float*)d_in[6];
  const float* w1g  = (const float*)d_in[7];
  const float* b1g  = (const float*)d_in[8];
  const float* w1c  = (const float*)d_in[9];
  const float* b1c  = (const float*)d_in[10];
  const float* wfc  = (const float*)d_in[11];
  const float* bfc  = (const float*)d_in[12];
  float* out = (float*)d_out;
  unsigned short* wt = (unsigned short*)d_ws;

  (void)hipFuncSetAttribute((const void*)dcgru,
                            hipFuncAttributeMaxDynamicSharedMemorySize, LDS_BYTES);
  setup_wt<<<dim3((WT_TOTAL + 255)/256), dim3(256), 0, stream>>>(w0g, w0c, w1g, w1c, wt);
  setup_s2<<<dim3(64), dim3(256), 0, stream>>>(sup, wt + S2_OFF);
  dcgru<<<dim3(B_), dim3(1024), LDS_BYTES, stream>>>(
      xseq, slen, sup, b0g, b0c, b1g, b1c, wfc, bfc, wt, out);
}

// Round 4
// 9890.795 us; speedup vs baseline: 1.5703x; 1.5703x over previous
//
#include <hip/hip_runtime.h>

// Problem constants
#define B_   32
#define T_   256
#define N_   128
#define DIN_ 16
#define U_   64

// LDS layout (ushort elements)
#define PD 392   // node-major diffusion buffer pitch (>=384, +8 stagger)
#define PT 136   // ch-major (transposed) buffer pitch (>=128, +8 stagger)
#define LDS_US  (N_*PD + N_*PT)
#define LDS_BYTES (LDS_US*2)     // 135168 B

// Workspace (ushort elems): WT[co][k], k-order: [dm0 c | (dm1,dm2) interleaved]
#define WT0G_OFF 0
#define WT0C_OFF (128*256)
#define WT1G_OFF (WT0C_OFF + 64*256)
#define WT1C_OFF (WT1G_OFF + 128*384)
#define WT_TOTAL (WT1C_OFF + 64*384)   // 122880 ushorts
#define S2_OFF   WT_TOTAL              // bf16 S2[128][128]

typedef __attribute__((ext_vector_type(8))) short bfrag;          // 8 bf16 (4 VGPR)
typedef __attribute__((ext_vector_type(4))) float ffrag;          // MFMA C/D
typedef __attribute__((ext_vector_type(4))) unsigned short us4;
typedef __attribute__((ext_vector_type(2))) unsigned short us2;

// Barrier that does NOT drain vmcnt: LDS ordering only (ds ops = lgkmcnt).
// Keeps cross-phase weight prefetches in flight (the __syncthreads vmcnt(0)
// drain was serializing every phase on L2 latency).
#define SYNC() asm volatile("s_waitcnt lgkmcnt(0)\n\ts_barrier" ::: "memory")

__device__ __forceinline__ unsigned short f2b(float x) {          // fp32 -> bf16 RNE
  union { float f; unsigned u; } v; v.f = x;
  return (unsigned short)((v.u + 0x7fffu + ((v.u >> 16) & 1u)) >> 16);
}
__device__ __forceinline__ float sigm(float x) {
  float e = __expf(-x);
  return __builtin_amdgcn_rcpf(1.f + e);
}
__device__ __forceinline__ float tanh_(float x) {
  float e = __expf(2.f * x);   // tanh = 1 - 2/(1+e^{2x}); saturates cleanly
  return 1.f - 2.f * __builtin_amdgcn_rcpf(1.f + e);
}

// k-order: k<cin -> dm0 (W0 - W2 fold); else j=k-cin: c=j>>1, j&1==0 -> W1, else 2*W2
// (x2 = 2*S2@xc - xc with S2 precomputed; -xc and 2* absorbed into weights)
__device__ __forceinline__ float wval(const float* w, int ncol, int cin,
                                      int co, int k) {
  if (k >= 3*cin) return 0.f;             // zero K-pad (L0: 240 -> 256)
  if (k < cin) return w[(k*3 + 0)*ncol + co] - w[(k*3 + 2)*ncol + co];
  int j = k - cin, c = j >> 1;
  if ((j & 1) == 0) return w[(c*3 + 1)*ncol + co];
  return 2.f * w[(c*3 + 2)*ncol + co];
}

__global__ void setup_wt(const float* __restrict__ w0g, const float* __restrict__ w0c,
                         const float* __restrict__ w1g, const float* __restrict__ w1c,
                         unsigned short* __restrict__ wt) {
  int i = blockIdx.x * blockDim.x + threadIdx.x;
  if (i >= WT_TOTAL) return;
  float v;
  if (i < WT0C_OFF) {
    int co = i >> 8, k = i & 255;
    v = wval(w0g, 128, 80, co, k);
  } else if (i < WT1G_OFF) {
    int j = i - WT0C_OFF; int co = j >> 8, k = j & 255;
    v = wval(w0c, 64, 80, co, k);
  } else if (i < WT1C_OFF) {
    int j = i - WT1G_OFF; int co = j / 384, k = j - co*384;
    v = wval(w1g, 128, 128, co, k);
  } else {
    int j = i - WT1C_OFF; int co = j / 384, k = j - co*384;
    v = wval(w1c, 64, 128, co, k);
  }
  wt[i] = f2b(v);
}

__global__ void setup_s2(const float* __restrict__ sup, unsigned short* __restrict__ s2) {
  int idx = blockIdx.x * blockDim.x + threadIdx.x;   // 16384
  int i = idx >> 7, j = idx & 127;
  float acc = 0.f;
#pragma unroll 4
  for (int k = 0; k < 128; ++k) acc += sup[i*128 + k] * sup[k*128 + j];
  s2[idx] = f2b(acc);
}

// Gate GEMM: wave owns m-tiles {2p,2p+1} x co-tiles {c4 (r), 4+c4 (u)}.
// bw[8] holds ks..ks+3 for both co-tiles, rolling in-place reload (burst of 8
// outstanding loads; first burst issued in the PREVIOUS phase).
template<int KT>
__device__ __forceinline__ void gateGemm(ffrag (&acc)[4], bfrag (&bw)[8],
    const unsigned short* __restrict__ arow0, const unsigned short* __restrict__ arow1,
    const unsigned short* __restrict__ bpr, const unsigned short* __restrict__ bpu,
    const int lq) {
#pragma unroll
  for (int ks = 0; ks < KT; ++ks) {
    const int k = ks & 3;
    bfrag a0 = *(const bfrag*)&arow0[32*ks + 8*lq];
    bfrag a1 = *(const bfrag*)&arow1[32*ks + 8*lq];
    bfrag br = bw[2*k], bu = bw[2*k+1];
    if (ks + 4 < KT) {
      bw[2*k]   = *(const bfrag*)&bpr[32*(ks+4) + 8*lq];
      bw[2*k+1] = *(const bfrag*)&bpu[32*(ks+4) + 8*lq];
    }
    acc[0] = __builtin_amdgcn_mfma_f32_16x16x32_bf16(a0, br, acc[0], 0,0,0);
    acc[1] = __builtin_amdgcn_mfma_f32_16x16x32_bf16(a1, br, acc[1], 0,0,0);
    acc[2] = __builtin_amdgcn_mfma_f32_16x16x32_bf16(a0, bu, acc[2], 0,0,0);
    acc[3] = __builtin_amdgcn_mfma_f32_16x16x32_bf16(a1, bu, acc[3], 0,0,0);
  }
}

template<int KT>
__device__ __forceinline__ void candGemm(ffrag (&acc)[2], bfrag (&bw)[4],
    const unsigned short* __restrict__ arow0, const unsigned short* __restrict__ arow1,
    const unsigned short* __restrict__ bpc, const int lq) {
#pragma unroll
  for (int ks = 0; ks < KT; ++ks) {
    const int k = ks & 3;
    bfrag a0 = *(const bfrag*)&arow0[32*ks + 8*lq];
    bfrag a1 = *(const bfrag*)&arow1[32*ks + 8*lq];
    bfrag bc = bw[k];
    if (ks + 4 < KT) bw[k] = *(const bfrag*)&bpc[32*(ks+4) + 8*lq];
    acc[0] = __builtin_amdgcn_mfma_f32_16x16x32_bf16(a0, bc, acc[0], 0,0,0);
    acc[1] = __builtin_amdgcn_mfma_f32_16x16x32_bf16(a1, bc, acc[1], 0,0,0);
  }
}

__global__ __launch_bounds__(1024, 4) void dcgru(
    const float* __restrict__ xseq, const int* __restrict__ slen,
    const float* __restrict__ sup,
    const float* __restrict__ b0g, const float* __restrict__ b0c,
    const float* __restrict__ b1g, const float* __restrict__ b1c,
    const float* __restrict__ wfc, const float* __restrict__ bfc,
    const unsigned short* __restrict__ wt, float* __restrict__ out) {
  extern __shared__ unsigned short lds[];
  unsigned short* diffb = lds;             // [128][PD] node-major A-operand buffer
  unsigned short* difT  = lds + N_*PD;     // [128][PT] ch-major (diffuse B operand)
  const int b   = blockIdx.x;
  const int tid = threadIdx.x;
  const int w   = tid >> 6;                // wave 0..15
  const int s8  = w >> 1;                  // diffuse role: m-tile (16 nodes)
  const int par = w & 1;                   // diffuse role: tile-list half
  const int p   = w >> 2;                  // GRU role: m-quad (nodes [32p,32p+32))
  const int c4  = w & 3;                   // GRU role: ch-tile [16c4,16c4+16)
  const int ln  = tid & 15;
  const int lq  = (tid >> 4) & 3;
  const int L   = slen[b];
  const unsigned short* __restrict__ arow0 = diffb + (32*p      + ln)*PD;
  const unsigned short* __restrict__ arow1 = diffb + (32*p + 16 + ln)*PD;

  // Weight row pointers for this wave's co-tiles
  const unsigned short* bpr0 = wt + WT0G_OFF + (16*c4       + ln)*256;
  const unsigned short* bpu0 = wt + WT0G_OFF + (16*(4 + c4) + ln)*256;
  const unsigned short* bpc0 = wt + WT0C_OFF + (16*c4       + ln)*256;
  const unsigned short* bpr1 = wt + WT1G_OFF + (16*c4       + ln)*384;
  const unsigned short* bpu1 = wt + WT1G_OFF + (16*(4 + c4) + ln)*384;
  const unsigned short* bpc1 = wt + WT1C_OFF + (16*c4       + ln)*384;

  // ---- S and S2 A-frags for the diffuse m-tile (8 bfrags = 32 VGPR) ----
  bfrag Sf[4], S2f[4];
#pragma unroll
  for (int ks = 0; ks < 4; ++ks) {
    const float* pS = sup + (16*s8 + ln)*N_ + 32*ks + 8*lq;
    union { bfrag v; unsigned short u[8]; } tmp;
#pragma unroll
    for (int j = 0; j < 8; ++j) tmp.u[j] = f2b(pS[j]);
    Sf[ks] = tmp.v;
    S2f[ks] = *(const bfrag*)&wt[S2_OFF + (16*s8 + ln)*N_ + 32*ks + 8*lq];
  }

  // Persistent per-wave biases (scalar per lane)
  const float bgr0 = b0g[16*c4 + ln], bgu0 = b0g[16*(4 + c4) + ln];
  const float bc0v = b0c[16*c4 + ln];
  const float bgr1 = b1g[16*c4 + ln], bgu1 = b1g[16*(4 + c4) + ln];
  const float bc1v = b1c[16*c4 + ln];

  // fp32 master hidden: value[node = 32p + 16i + 4lq + r][ch = 16c4 + ln]
  ffrag h0m[2], h1m[2];
  const ffrag fz = {0.f, 0.f, 0.f, 0.f};
#pragma unroll
  for (int i = 0; i < 2; ++i) { h0m[i] = fz; h1m[i] = fz; }

  // zero L0 K-pad cols [240,256) once
  for (int i = tid; i < N_*16; i += 1024)
    diffb[(i >> 4)*PD + 240 + (i & 15)] = 0;

  // Diffusion for ch tile nt (m-tile s8): dm1 = S@xc, dm2 = S2@xc -> interleaved
  // cols dbase + 2*ch + {0,1}.
  auto diffuse = [&](int nt, int dbase) {
    ffrag a1 = fz, a2 = fz;
#pragma unroll
    for (int ks = 0; ks < 4; ++ks) {
      bfrag bf = *(const bfrag*)&difT[(16*nt + ln)*PT + 32*ks + 8*lq];
      a1 = __builtin_amdgcn_mfma_f32_16x16x32_bf16(Sf[ks],  bf, a1, 0,0,0);
      a2 = __builtin_amdgcn_mfma_f32_16x16x32_bf16(S2f[ks], bf, a2, 0,0,0);
    }
    const int node0 = 16*s8 + 4*lq;
    const int col = dbase + 2*(16*nt + ln);
#pragma unroll
    for (int r = 0; r < 4; ++r) {
      us2 pq = {f2b(a1[r]), f2b(a2[r])};
      *(us2*)&diffb[(node0 + r)*PD + col] = pq;    // aligned b32 write
    }
  };

  // Dump this wave's GRU cell (2 m-tiles x ch-tile c4) into both LDS layouts.
  auto dumpC = [&](ffrag (&v)[2], int cb) {
    const int ch = cb + 16*c4 + ln;
#pragma unroll
    for (int i = 0; i < 2; ++i) {
      const int node0 = 32*p + 16*i + 4*lq;
      unsigned short sv[4];
#pragma unroll
      for (int r = 0; r < 4; ++r) sv[r] = f2b(v[i][r]);
#pragma unroll
      for (int r = 0; r < 4; ++r) diffb[(node0 + r)*PD + ch] = sv[r];
      us4 p4 = {sv[0], sv[1], sv[2], sv[3]};
      *(us4*)&difT[ch*PT + node0] = p4;
    }
  };

  auto prebG = [&](bfrag (&bw)[8], const unsigned short* bpr,
                   const unsigned short* bpu) {
#pragma unroll
    for (int k = 0; k < 4; ++k) {
      bw[2*k]   = *(const bfrag*)&bpr[32*k + 8*lq];
      bw[2*k+1] = *(const bfrag*)&bpu[32*k + 8*lq];
    }
  };
  auto prebC = [&](bfrag (&bw)[4], const unsigned short* bpc) {
#pragma unroll
    for (int k = 0; k < 4; ++k) bw[k] = *(const bfrag*)&bpc[32*k + 8*lq];
  };

  // x prefetch: 2 floats/thread
  float2 xv = *(const float2*)&xseq[(size_t)(b*T_)*N_*DIN_ + 2*tid];

  bfrag bw8[8];   // gate burst ring
  bfrag bw4[4];   // cand burst ring

#pragma clang loop unroll(disable)
  for (int t = 0; t < L; ++t) {
    ffrag u0s[2], u1s[2];
    // ======== Layer 0 (cols: x 0..15 | h 16..79 | dm12 80..239 | pad) ========
    {  // P1: stage x_t, dump h0, prefetch next x + first gate burst
      const int f = 2*tid;
      const int node = f >> 4, c = f & 15;
      unsigned short s0 = f2b(xv.x), s1 = f2b(xv.y);
      us2 q = {s0, s1};
      *(us2*)&diffb[node*PD + c] = q;
      difT[c*PT + node] = s0; difT[(c+1)*PT + node] = s1;
      dumpC(h0m, DIN_);
      int tn = t + 1 < L ? t + 1 : L - 1;
      xv = *(const float2*)&xseq[(size_t)(b*T_ + tn)*N_*DIN_ + 2*tid];
      prebG(bw8, bpr0, bpu0);
    }
    SYNC();                                            // B1
    if (par == 0) { diffuse(0, 80); diffuse(1, 80); diffuse(2, 80); }
    else          { diffuse(3, 80); diffuse(4, 80); }
    SYNC();                                            // B2
    {  // P3: gate GEMM + activations (rh stays in regs until B3)
      ffrag ga[4] = {fz, fz, fz, fz};
      gateGemm<8>(ga, bw8, arow0, arow1, bpr0, bpu0, lq);
      ffrag rh[2];
#pragma unroll
      for (int i = 0; i < 2; ++i)
#pragma unroll
        for (int r = 0; r < 4; ++r) {
          float rr = sigm(ga[i][r] + bgr0);
          rh[i][r] = rr * h0m[i][r];
          u0s[i][r] = sigm(ga[2+i][r] + bgu0);
        }
      SYNC();                                          // B3 (h-col reads done)
      dumpC(rh, DIN_);                                 // P4: overwrite h-cols
      prebC(bw4, bpc0);
    }
    SYNC();                                            // B4
    if (par == 0) { diffuse(1, 80); diffuse(2, 80); }
    else          { diffuse(3, 80); diffuse(4, 80); }
    SYNC();                                            // B5
    {  // P6: candidate GEMM + state update
      ffrag ca[2] = {fz, fz};
      candGemm<8>(ca, bw4, arow0, arow1, bpc0, lq);
#pragma unroll
      for (int i = 0; i < 2; ++i)
#pragma unroll
        for (int r = 0; r < 4; ++r) {
          float cc = tanh_(ca[i][r] + bc0v);
          float uu = u0s[i][r];
          h0m[i][r] = uu*h0m[i][r] + (1.f - uu)*cc;
        }
    }
    SYNC();                                            // B6
    // ======== Layer 1 (cols: h0' 0..63 | h1 64..127 | dm12 128..383) ========
    dumpC(h0m, 0);
    dumpC(h1m, 64);
    prebG(bw8, bpr1, bpu1);
    SYNC();                                            // B7
    if (par == 0) { diffuse(0, 128); diffuse(1, 128); diffuse(2, 128); diffuse(3, 128); }
    else          { diffuse(4, 128); diffuse(5, 128); diffuse(6, 128); diffuse(7, 128); }
    SYNC();                                            // B8
    {
      ffrag ga[4] = {fz, fz, fz, fz};
      gateGemm<12>(ga, bw8, arow0, arow1, bpr1, bpu1, lq);
      ffrag rh[2];
#pragma unroll
      for (int i = 0; i < 2; ++i)
#pragma unroll
        for (int r = 0; r < 4; ++r) {
          float rr = sigm(ga[i][r] + bgr1);
          rh[i][r] = rr * h1m[i][r];
          u1s[i][r] = sigm(ga[2+i][r] + bgu1);
        }
      SYNC();                                          // B9
      dumpC(rh, 64);
      prebC(bw4, bpc1);
    }
    SYNC();                                            // B10
    if (par == 0) { diffuse(4, 128); diffuse(5, 128); }
    else          { diffuse(6, 128); diffuse(7, 128); }
    SYNC();                                            // B11
    {
      ffrag ca[2] = {fz, fz};
      candGemm<12>(ca, bw4, arow0, arow1, bpc1, lq);
#pragma unroll
      for (int i = 0; i < 2; ++i)
#pragma unroll
        for (int r = 0; r < 4; ++r) {
          float cc = tanh_(ca[i][r] + bc1v);
          float uu = u1s[i][r];
          h1m[i][r] = uu*h1m[i][r] + (1.f - uu)*cc;
        }
    }
    SYNC();                                            // B12
  }

  // ---------------- Head: relu(h1) @ W_fc + b_fc, max over nodes --------------
  {
    float* hb = (float*)lds;                 // [128][64] relu'd last hidden
#pragma unroll
    for (int i = 0; i < 2; ++i)
#pragma unroll
      for (int r = 0; r < 4; ++r) {
        float v = h1m[i][r];
        hb[(32*p + 16*i + 4*lq + r)*U_ + 16*c4 + ln] = v > 0.f ? v : 0.f;
      }
  }
  SYNC();
  float* hb = (float*)lds;
  float* lb = hb + N_*U_;                    // [128][4] logits
  if (tid < N_) {
    float lg[4];
#pragma unroll
    for (int j = 0; j < 4; ++j) lg[j] = bfc[j];
    for (int ch = 0; ch < U_; ++ch) {
      float v = hb[tid*U_ + ch];
#pragma unroll
      for (int j = 0; j < 4; ++j) lg[j] += v * wfc[ch*4 + j];
    }
#pragma unroll
    for (int j = 0; j < 4; ++j) lb[tid*4 + j] = lg[j];
  }
  SYNC();
  if (tid < 4) {
    float m = lb[tid];
    for (int n = 1; n < N_; ++n) m = fmaxf(m, lb[n*4 + tid]);
    out[b*4 + tid] = m;
  }
}

extern "C" void kernel_launch(void* const* d_in, const int* in_sizes, int n_in,
                              void* d_out, int out_size, void* d_ws, size_t ws_size,
                              hipStream_t stream) {
  const float* xseq = (const float*)d_in[0];
  const int*   slen = (const int*)  d_in[1];
  const float* sup  = (const float*)d_in[2];
  const float* w0g  = (const float*)d_in[3];
  const float* b0g  = (const float*)d_in[4];
  const float* w0c  = (const float*)d_in[5];
  const float* b0c  = (const float*)d_in[6];
  const float* w1g  = (const float*)d_in[7];
  const float* b1g  = (const float*)d_in[8];
  const float* w1c  = (const float*)d_in[9];
  const float* b1c  = (const float*)d_in[10];
  const float* wfc  = (const float*)d_in[11];
  const float* bfc  = (const float*)d_in[12];
  float* out = (float*)d_out;
  unsigned short* wt = (unsigned short*)d_ws;

  (void)hipFuncSetAttribute((const void*)dcgru,
                            hipFuncAttributeMaxDynamicSharedMemorySize, LDS_BYTES);
  setup_wt<<<dim3((WT_TOTAL + 255)/256), dim3(256), 0, stream>>>(w0g, w0c, w1g, w1c, wt);
  setup_s2<<<dim3(64), dim3(256), 0, stream>>>(sup, wt + S2_OFF);
  dcgru<<<dim3(B_), dim3(1024), LDS_BYTES, stream>>>(
      xseq, slen, sup, b0g, b0c, b1g, b1c, wfc, bfc, wt, out);
}